// Round 6
// baseline (21207.091 us; speedup 1.0000x reference)
//
#include <hip/hip_runtime.h>
#include <math.h>

#define NBLK 64
#define NTHR 512

typedef float vf4 __attribute__((ext_vector_type(4)));

namespace spinn {

constexpr int Ss = 48, Hh = 256, TT = 96, Mm = 193, H3 = 768, MLPD = 1024;

__device__ __forceinline__ float sigf(float x) { return 1.0f / (1.0f + expf(-x)); }

#define FMA4(acc, a, b)                         \
    {                                           \
        acc.x = fmaf((a).x, (b).x, acc.x);      \
        acc.y = fmaf((a).y, (b).y, acc.y);      \
        acc.z = fmaf((a).z, (b).z, acc.z);      \
        acc.w = fmaf((a).w, (b).w, acc.w);      \
    }

__device__ __forceinline__ float wave_iscan(float v, int lane) {
    #pragma unroll
    for (int off = 1; off < 64; off <<= 1) {
        float u = __shfl_up(v, off, 64);
        if (lane >= off) v += u;
    }
    return v;
}
__device__ __forceinline__ float wred64(float v) {
    #pragma unroll
    for (int off = 1; off < 64; off <<= 1) v += __shfl_xor(v, off, 64);
    return v;
}
__device__ __forceinline__ float wred16(float v) {  // reduce within 16-lane group
    v += __shfl_xor(v, 1, 64);
    v += __shfl_xor(v, 2, 64);
    v += __shfl_xor(v, 4, 64);
    v += __shfl_xor(v, 8, 64);
    return v;
}

}  // namespace spinn

using namespace spinn;

// One block per element. All state block-local (LDS + private global V).
// No inter-block communication anywhere -> no global barriers, no coherent ops.
__global__ void __launch_bounds__(NTHR, 1) spinn_kernel(
    const int* __restrict__ x, const float* __restrict__ emb,
    const float* __restrict__ wih, const float* __restrict__ whh,
    const float* __restrict__ bih, const float* __restrict__ bhh,
    const float* __restrict__ aw, const float* __restrict__ ab,
    const float* __restrict__ tlw, const float* __restrict__ tlb,
    const float* __restrict__ trw, const float* __restrict__ trb,
    const float* __restrict__ l0w, const float* __restrict__ l0b,
    const float* __restrict__ l1w, const float* __restrict__ l1b,
    const float* __restrict__ l2w, const float* __restrict__ l2b,
    float* __restrict__ out, float* __restrict__ wsf)
{
    const int tid  = threadIdx.x;
    const int e    = blockIdx.x;          // element
    const int wave = tid >> 6;            // 0..7
    const int lane = tid & 63;
    const int l16  = lane & 15;
    const int g    = lane >> 4;           // 4 row-groups per wave

    // private V stack in global workspace: [193][256] + 64 pad floats
    float* Vg = wsf + (size_t)e * (Mm * 256 + 64);

    // ---- LDS (~78 KB) ----
    __shared__ float s_B[Ss * 256];       // embedding rows for this element
    __shared__ float s_xt[H3];            // [x_b | x1 | x2]
    __shared__ float s_h[256], s_c[256];
    __shared__ float s_g[1024];           // LSTM gate preacts; reused as y0
    __shared__ float s_tg[1280];          // tree gate preacts; reused as y1
    __shared__ float s_r1[256], s_r2[256];
    __shared__ float s_s[208];            // stack strengths (193 used)
    __shared__ float sw1[208], sw2[208];  // pop weights
    __shared__ float pw1[208], pw2[208];  // push weights (FULL, incl idx/idx2)
    __shared__ float s_sb[Ss], s_wb[Ss], s_wbe[Ss];
    __shared__ float s_alpha[2];
    __shared__ float s_bias[1024];        // bih+bhh
    __shared__ float s_tbias[1280];       // tlb+trb

    // ================= INIT =================
    {
        // embedding gather (vf4-coalesced within each token row)
        for (int i = tid; i < Ss * 64; i += NTHR) {
            int s = i >> 6, c = i & 63;
            int tok = x[e * Ss + s];
            ((vf4*)s_B)[i] = ((const vf4*)emb)[(size_t)tok * 64 + c];
        }
        if (tid < Ss) s_sb[tid] = (x[e * Ss + tid] > 0) ? 1.0f : 0.0f;
        for (int i = tid; i < 208; i += NTHR) s_s[i] = 0.0f;
        if (tid < 256) { s_h[tid] = 0.0f; s_c[tid] = 0.0f; }
        for (int i = tid; i < 1024; i += NTHR) s_bias[i] = bih[i] + bhh[i];
        for (int i = tid; i < 1280; i += NTHR) s_tbias[i] = tlb[i] + trb[i];
        for (int i = tid; i < Mm * 256; i += NTHR) Vg[i] = 0.0f;  // kill stale NaNs
        __syncthreads();
        if (wave == 0) {  // buffer read with alpha=1 -> wbe
            float sbv = (lane < Ss) ? s_sb[lane] : 0.0f;
            float P = wave_iscan(sbv, lane);
            float wbe = fminf(P, 1.0f) - fminf(P - sbv, 1.0f);
            if (lane < Ss) s_wbe[lane] = wbe;
        }
        __syncthreads();
        if (tid < 256) {
            float a = 0.0f;
            #pragma unroll 8
            for (int s = 0; s < Ss; s++) a = fmaf(s_wbe[s], s_B[s * 256 + tid], a);
            s_xt[tid] = a;
            s_xt[256 + tid] = 0.0f;
            s_xt[512 + tid] = 0.0f;
        }
        __syncthreads();
    }

    // ================= time loop (no global barriers) =================
    for (int t = 0; t < TT; t++) {
        const int idx  = 191 - 2 * t;
        const int idx2 = idx - 1;

        // ---------- LSTM gates: 1024 rows, K=768+256; 4 rows/pass/wave ----------
        {
            const vf4* xt4 = (const vf4*)s_xt;
            const vf4* h4  = (const vf4*)s_h;
            #pragma unroll 2
            for (int p = 0; p < 32; p++) {
                int row = wave * 128 + p * 4 + g;
                const vf4* w  = (const vf4*)wih + (size_t)row * 192 + l16;
                const vf4* wh = (const vf4*)whh + (size_t)row * 64 + l16;
                vf4 acc = {0.f, 0.f, 0.f, 0.f};
                #pragma unroll
                for (int j = 0; j < 12; j++) { vf4 wv = w[j * 16], xv = xt4[l16 + j * 16]; FMA4(acc, wv, xv); }
                #pragma unroll
                for (int j = 0; j < 4; j++)  { vf4 wv = wh[j * 16], hv = h4[l16 + j * 16]; FMA4(acc, wv, hv); }
                float sv = wred16(acc.x + acc.y + acc.z + acc.w);
                if (l16 == 0) s_g[row] = sv + s_bias[row];
            }
        }
        __syncthreads();
        if (tid < 256) {  // gate combine
            float gi = s_g[tid], gf = s_g[256 + tid], gg = s_g[512 + tid], go = s_g[768 + tid];
            float cv = sigf(gf) * s_c[tid] + sigf(gi) * tanhf(gg);
            s_c[tid] = cv;
            s_h[tid] = sigf(go) * tanhf(cv);
        }
        __syncthreads();
        // ---------- alpha logits (wave 0) ----------
        if (wave == 0) {
            vf4 hv = ((const vf4*)s_h)[lane];
            vf4 a0 = ((const vf4*)aw)[lane];
            vf4 a1 = ((const vf4*)aw)[64 + lane];
            float lg0 = hv.x * a0.x + hv.y * a0.y + hv.z * a0.z + hv.w * a0.w;
            float lg1 = hv.x * a1.x + hv.y * a1.y + hv.z * a1.z + hv.w * a1.w;
            lg0 = wred64(lg0);
            lg1 = wred64(lg1);
            if (lane == 0) {
                lg0 += ab[0]; lg1 += ab[1];
                s_alpha[0] = 1.0f / (1.0f + expf(10.0f * (lg1 - lg0)));  // a_r
                s_alpha[1] = 1.0f / (1.0f + expf(10.0f * (lg0 - lg1)));  // a_s
            }
        }
        __syncthreads();
        const float a_r = s_alpha[0], a_s = s_alpha[1];
        // ---------- scans: wave 0 = stack, wave 1 = buffer ----------
        if (wave == 0) {
            int m0 = lane * 4;
            float v0 = (m0     < Mm) ? s_s[m0]     : 0.0f;
            float v1 = (m0 + 1 < Mm) ? s_s[m0 + 1] : 0.0f;
            float v2 = (m0 + 2 < Mm) ? s_s[m0 + 2] : 0.0f;
            float v3 = (m0 + 3 < Mm) ? s_s[m0 + 3] : 0.0f;
            float c1 = v0 + v1, c2 = c1 + v2, c3 = c2 + v3;
            float inc = c3;
            #pragma unroll
            for (int off = 1; off < 64; off <<= 1) {
                float u = __shfl_up(inc, off, 64);
                if (lane >= off) inc += u;
            }
            float ex = inc - c3;
            float Pv[4]  = {ex + v0, ex + c1, ex + c2, ex + c3};
            float Pp[4]  = {ex, ex + v0, ex + c1, ex + c2};
            float vv_[4] = {v0, v1, v2, v3};
            float sn[4];
            #pragma unroll
            for (int i = 0; i < 4; i++) {
                int m = m0 + i;
                float w1 = fminf(Pv[i], a_r) - fminf(Pp[i], a_r);
                float wt = fminf(Pv[i], 1.0f + a_r) - fminf(Pp[i], 1.0f + a_r);
                float s2 = vv_[i] - wt;
                if (m == idx)  s2 = a_r;   // this step's pushes (set after pop)
                if (m == idx2) s2 = a_s;
                sn[i] = s2;
                if (m < Mm) {
                    sw1[m] = w1;
                    sw2[m] = wt - w1;
                    s_s[m] = s2;
                }
            }
            // push scan (alpha = 1) on updated s; pw FULL (V[idx],V[idx2] are
            // written before the push V-loop runs -> no deferred fixes needed)
            float d1 = sn[0] + sn[1], d2 = d1 + sn[2], d3 = d2 + sn[3];
            float inc2 = d3;
            #pragma unroll
            for (int off = 1; off < 64; off <<= 1) {
                float u = __shfl_up(inc2, off, 64);
                if (lane >= off) inc2 += u;
            }
            float ex2 = inc2 - d3;
            float Qv[4] = {ex2 + sn[0], ex2 + d1, ex2 + d2, ex2 + d3};
            float Qp[4] = {ex2, ex2 + sn[0], ex2 + d1, ex2 + d2};
            #pragma unroll
            for (int i = 0; i < 4; i++) {
                int m = m0 + i;
                if (m < Mm) {
                    float w1e = fminf(Qv[i], 1.0f) - fminf(Qp[i], 1.0f);
                    float w2e = (fminf(Qv[i], 2.0f) - fminf(Qp[i], 2.0f)) - w1e;
                    pw1[m] = w1e;
                    pw2[m] = w2e;
                }
            }
        } else if (wave == 1) {
            float sbv = (lane < Ss) ? s_sb[lane] : 0.0f;
            float Pb = wave_iscan(sbv, lane);
            float wb = fminf(Pb, a_s) - fminf(Pb - sbv, a_s);
            float sbn = sbv - wb;
            float Pb2 = wave_iscan(sbn, lane);
            float wbe = fminf(Pb2, 1.0f) - fminf(Pb2 - sbn, 1.0f);
            if (lane < Ss) { s_sb[lane] = sbn; s_wb[lane] = wb; s_wbe[lane] = wbe; }
        }
        __syncthreads();
        // ---------- pop V-loop: r1/r2 (sw weights; sw[idx]=sw[idx2]=0 by math) ----------
        {
            int dw = wave * 32 + (lane & 31);
            int mh = lane >> 5;
            int mA = mh ? 97 : 0, mB = mh ? Mm : 97;
            float a1 = 0.0f, a2 = 0.0f;
            for (int m = mA; m < mB; m++) {
                float vv = Vg[m * 256 + dw];
                a1 = fmaf(sw1[m], vv, a1);
                a2 = fmaf(sw2[m], vv, a2);
            }
            a1 += __shfl_xor(a1, 32, 64);
            a2 += __shfl_xor(a2, 32, 64);
            if (lane < 32) { s_r1[dw] = a1; s_r2[dw] = a2; }
        }
        // ---------- buffer dots (tid<256): buf -> V[idx2], axb -> xt[0:256] ----------
        // (races only with zero-weight Vg[idx2] reads above; stored value finite)
        if (tid < 256) {
            float abf = 0.0f, axb = 0.0f;
            #pragma unroll 8
            for (int s = 0; s < Ss; s++) {
                float be = s_B[s * 256 + tid];
                abf = fmaf(s_wb[s], be, abf);
                axb = fmaf(s_wbe[s], be, axb);
            }
            Vg[idx2 * 256 + tid] = abf;
            s_xt[tid] = axb;
        }
        __syncthreads();
        // ---------- tree gates: 1280 rows, K=512 ----------
        {
            const vf4* r14 = (const vf4*)s_r1;
            const vf4* r24 = (const vf4*)s_r2;
            #pragma unroll 2
            for (int p = 0; p < 40; p++) {
                int row = wave * 160 + p * 4 + g;
                const vf4* wl = (const vf4*)tlw + (size_t)row * 64 + l16;
                const vf4* wr = (const vf4*)trw + (size_t)row * 64 + l16;
                vf4 acc = {0.f, 0.f, 0.f, 0.f};
                #pragma unroll
                for (int j = 0; j < 4; j++) {
                    vf4 u = wl[j * 16], r1v = r14[l16 + j * 16]; FMA4(acc, u, r1v);
                    vf4 v = wr[j * 16], r2v = r24[l16 + j * 16]; FMA4(acc, v, r2v);
                }
                float sv = wred16(acc.x + acc.y + acc.z + acc.w);
                if (l16 == 0) s_tg[row] = sv + s_tbias[row];
            }
        }
        __syncthreads();
        if (tid < 256) {  // tree combine -> ht -> V[idx]
            float ta  = s_tg[tid];
            float ti  = s_tg[256 + tid];
            float tf1 = s_tg[512 + tid];
            float tf2 = s_tg[768 + tid];
            float to  = s_tg[1024 + tid];
            float ct = tanhf(ta) * sigf(ti) + sigf(tf1) * s_r1[tid] + sigf(tf2) * s_r2[tid];
            Vg[idx * 256 + tid] = sigf(to) * tanhf(ct);
        }
        __syncthreads();
        // ---------- push V-loop: x1/x2 over NEW V (incl idx/idx2), full pw ----------
        {
            int dw = wave * 32 + (lane & 31);
            int mh = lane >> 5;
            int mA = mh ? 97 : 0, mB = mh ? Mm : 97;
            float x1 = 0.0f, x2 = 0.0f;
            for (int m = mA; m < mB; m++) {
                float vv = Vg[m * 256 + dw];
                x1 = fmaf(pw1[m], vv, x1);
                x2 = fmaf(pw2[m], vv, x2);
            }
            x1 += __shfl_xor(x1, 32, 64);
            x2 += __shfl_xor(x2, 32, 64);
            if (lane < 32) { s_xt[256 + dw] = x1; s_xt[512 + dw] = x2; }
        }
        __syncthreads();
    }

    // ================= MLP head (block-local; input = s_xt[256:512]) =================
    {   // layer 0: 1024 rows, K=256 -> s_g
        const vf4* xin4 = (const vf4*)(s_xt + 256);
        #pragma unroll 4
        for (int p = 0; p < 32; p++) {
            int row = wave * 128 + p * 4 + g;
            const vf4* w = (const vf4*)l0w + (size_t)row * 64 + l16;
            vf4 acc = {0.f, 0.f, 0.f, 0.f};
            #pragma unroll
            for (int j = 0; j < 4; j++) { vf4 wv = w[j * 16], xv = xin4[l16 + j * 16]; FMA4(acc, wv, xv); }
            float sv = wred16(acc.x + acc.y + acc.z + acc.w);
            if (l16 == 0) s_g[row] = fmaxf(sv + l0b[row], 0.0f);
        }
    }
    __syncthreads();
    {   // layer 1: 1024 rows, K=1024 -> s_tg
        const vf4* y4 = (const vf4*)s_g;
        #pragma unroll 2
        for (int p = 0; p < 32; p++) {
            int row = wave * 128 + p * 4 + g;
            const vf4* w = (const vf4*)l1w + (size_t)row * 256 + l16;
            vf4 acc = {0.f, 0.f, 0.f, 0.f};
            #pragma unroll
            for (int j = 0; j < 16; j++) { vf4 wv = w[j * 16], yv = y4[l16 + j * 16]; FMA4(acc, wv, yv); }
            float sv = wred16(acc.x + acc.y + acc.z + acc.w);
            if (l16 == 0) s_tg[row] = fmaxf(sv + l1b[row], 0.0f);
        }
    }
    __syncthreads();
    if (tid < 192) {  // layer 2: 3 rows, K=1024
        int r = tid >> 6;
        const vf4* w  = (const vf4*)l2w + (size_t)r * 256;
        const vf4* y4 = (const vf4*)s_tg;
        vf4 acc = {0.f, 0.f, 0.f, 0.f};
        #pragma unroll
        for (int j = 0; j < 4; j++) { vf4 wv = w[lane + j * 64], yv = y4[lane + j * 64]; FMA4(acc, wv, yv); }
        float sv = wred64(acc.x + acc.y + acc.z + acc.w);
        if (lane == 0) out[e * 3 + r] = sv + l2b[r];
    }
}

extern "C" void kernel_launch(void* const* d_in, const int* in_sizes, int n_in,
                              void* d_out, int out_size, void* d_ws, size_t ws_size,
                              hipStream_t stream) {
    (void)in_sizes; (void)n_in; (void)out_size; (void)ws_size;

    const int*   x_   = (const int*)d_in[0];
    const float* emb  = (const float*)d_in[1];
    const float* wih  = (const float*)d_in[2];
    const float* whh  = (const float*)d_in[3];
    const float* bih  = (const float*)d_in[4];
    const float* bhh  = (const float*)d_in[5];
    const float* aw   = (const float*)d_in[6];
    const float* ab   = (const float*)d_in[7];
    const float* tlw  = (const float*)d_in[8];
    const float* tlb  = (const float*)d_in[9];
    const float* trw  = (const float*)d_in[10];
    const float* trb  = (const float*)d_in[11];
    const float* l0w  = (const float*)d_in[12];
    const float* l0b  = (const float*)d_in[13];
    const float* l1w  = (const float*)d_in[14];
    const float* l1b  = (const float*)d_in[15];
    const float* l2w  = (const float*)d_in[16];
    const float* l2b  = (const float*)d_in[17];

    spinn_kernel<<<dim3(NBLK), dim3(NTHR), 0, stream>>>(
        x_, emb, wih, whh, bih, bhh, aw, ab, tlw, tlb, trw, trb,
        l0w, l0b, l1w, l1b, l2w, l2b, (float*)d_out, (float*)d_ws);
}

// Round 7
// 3184.904 us; speedup vs baseline: 6.6586x; 6.6586x over previous
//
#include <hip/hip_runtime.h>
#include <math.h>

#define NBLK 1024
#define NTHR 256

typedef float vf4 __attribute__((ext_vector_type(4)));

namespace spinn {

constexpr int Ss = 48, Hh = 256, TT = 96, Mm = 193, H3 = 768, MLPD = 1024;

__device__ __forceinline__ float sigf(float x) { return 1.0f / (1.0f + expf(-x)); }

#define FMA4(acc, a, b)                         \
    {                                           \
        acc.x = fmaf((a).x, (b).x, acc.x);      \
        acc.y = fmaf((a).y, (b).y, acc.y);      \
        acc.z = fmaf((a).z, (b).z, acc.z);      \
        acc.w = fmaf((a).w, (b).w, acc.w);      \
    }

// ---- coherent (device-scope) access helpers ----
__device__ __forceinline__ void st_co(float* p, float v) {
    asm volatile("global_store_dword %0, %1, off sc0 sc1" :: "v"(p), "v"(v) : "memory");
}
__device__ __forceinline__ void ld_co_v4_1(const vf4* p0, vf4& r0) {
    asm volatile("global_load_dwordx4 %0, %1, off sc0 sc1\n\t"
                 "s_waitcnt vmcnt(0)"
                 : "=&v"(r0) : "v"(p0) : "memory");
}
__device__ __forceinline__ void ld_co_f1x4(const float* p0, const float* p1, const float* p2,
                                           const float* p3, float& r0, float& r1, float& r2, float& r3) {
    asm volatile("global_load_dword %0, %4, off sc0 sc1\n\t"
                 "global_load_dword %1, %5, off sc0 sc1\n\t"
                 "global_load_dword %2, %6, off sc0 sc1\n\t"
                 "global_load_dword %3, %7, off sc0 sc1\n\t"
                 "s_waitcnt vmcnt(0)"
                 : "=&v"(r0), "=&v"(r1), "=&v"(r2), "=&v"(r3)
                 : "v"(p0), "v"(p1), "v"(p2), "v"(p3) : "memory");
}
__device__ __forceinline__ unsigned ld_co_u32(const unsigned* p) {
    unsigned r;
    asm volatile("global_load_dword %0, %1, off sc0 sc1\n\t"
                 "s_waitcnt vmcnt(0)"
                 : "=&v"(r) : "v"(p) : "memory");
    return r;
}

// ---- per-group (16-block) barrier ----
__device__ __forceinline__ void gbar(unsigned* cnt, unsigned tgt) {
    asm volatile("s_waitcnt vmcnt(0)" ::: "memory");
    __syncthreads();
    if (threadIdx.x == 0) {
        unsigned one = 1u;
        asm volatile("global_atomic_add %0, %1, off" :: "v"(cnt), "v"(one) : "memory");
        while (ld_co_u32(cnt) < tgt) __builtin_amdgcn_s_sleep(1);
    }
    __syncthreads();
}

// ---- wave-level primitives ----
__device__ __forceinline__ float wave_iscan(float v, int lane) {
    #pragma unroll
    for (int off = 1; off < 64; off <<= 1) {
        float u = __shfl_up(v, off, 64);
        if (lane >= off) v += u;
    }
    return v;
}
__device__ __forceinline__ float wred64(float v) {
    #pragma unroll
    for (int off = 1; off < 64; off <<= 1) v += __shfl_xor(v, off, 64);
    return v;
}
__device__ __forceinline__ float wred_ms(float v) {  // reduce over lane bits 4,5
    v += __shfl_xor(v, 16, 64);
    v += __shfl_xor(v, 32, 64);
    return v;
}

}  // namespace spinn

using namespace spinn;

// Block (e, q): element e = bid>>4, dim-slice q = bid&15 (16 dims).
// q-slicing keeps each XCD's weight working set L2-resident (round-6 lesson).
// V stack lives entirely in LDS (round-6 discovery). 4 blocks/CU.
__global__ void __launch_bounds__(NTHR, 4) spinn_kernel(
    const int* __restrict__ x, const float* __restrict__ emb,
    const float* __restrict__ wih, const float* __restrict__ whh,
    const float* __restrict__ bih, const float* __restrict__ bhh,
    const float* __restrict__ aw, const float* __restrict__ ab,
    const float* __restrict__ tlw, const float* __restrict__ tlb,
    const float* __restrict__ trw, const float* __restrict__ trb,
    const float* __restrict__ l0w, const float* __restrict__ l0b,
    const float* __restrict__ l1w, const float* __restrict__ l1b,
    const float* __restrict__ l2w, const float* __restrict__ l2b,
    float* __restrict__ out, float* __restrict__ wsf, unsigned* __restrict__ bar)
{
    const int tid  = threadIdx.x;
    const int bid  = blockIdx.x;
    const int e    = bid >> 4;        // element 0..63 (= group)
    const int q    = bid & 15;        // dim slice
    const int db   = q * 16;
    const int wave = tid >> 6;        // 0..3
    const int lane = tid & 63;
    const int ms   = lane >> 4;
    const int dl   = lane & 15;

    unsigned* cnt = bar + e * 32;     // per-group counter, 128B apart
    unsigned barnum = 0;

    // ---- global workspace (exchange buffers only) ----
    float* XTg = wsf;                 // [64][768]
    float* Hbg = XTg + 64 * H3;       // [64][256]
    float* R1g = Hbg + 64 * Hh;       // [64][256]
    float* R2g = R1g + 64 * Hh;       // [64][256]
    float* Y0g = R2g + 64 * Hh;       // [64][1024]
    float* Y1g = Y0g + 64 * MLPD;     // [64][1024]

    // ---- LDS (~28 KB) ----
    __shared__ float s_V[196 * 16];   // V stack slice [196 m][16 d] (rows 193..195 = 0)
    __shared__ float s_B[Ss * 16];    // embedding slice [48][16]
    __shared__ float s_xt[H3];        // staged full xt
    __shared__ float s_h[256];        // staged full h (T1 -> next L)
    __shared__ float s_c[16];         // own-slice cell state
    __shared__ float s_g[64];         // LSTM gate preacts (4 gates x 16 d)
    __shared__ float s_tg[80];        // tree gate preacts (5 gates x 16 d)
    __shared__ float s_r1[256], s_r2[256];   // staged full r1/r2
    __shared__ float s_s[208];        // stack strengths (193 used)
    __shared__ float sw1[208], sw2[208];     // pop weights  (zeros at 193..207)
    __shared__ float pw1[208], pw2[208];     // push weights (zeros at 193..207)
    __shared__ float s_sb[Ss], s_wb[Ss], s_wbe[Ss];
    __shared__ float s_bias[64];      // bih+bhh own rows
    __shared__ float s_tbias[80];     // tlb+trb own rows

    float* s_y = s_V;                 // MLP staging alias (V dead after loop)

    // ================= INIT =================
    {
        if (tid < 192) {              // embedding gather: 48 tokens x 4 vf4
            int s = tid >> 2, j = tid & 3;
            int tok = x[e * Ss + s];
            ((vf4*)s_B)[tid] = ((const vf4*)emb)[(size_t)tok * 64 + q * 4 + j];
        }
        if (tid < Ss) s_sb[tid] = (x[e * Ss + tid] > 0) ? 1.0f : 0.0f;
        for (int i = tid; i < 208; i += NTHR) s_s[i] = 0.0f;
        if (tid < 256) s_h[tid] = 0.0f;
        if (tid < 16) s_c[tid] = 0.0f;
        if (tid < 64) {
            int row = (tid >> 4) * Hh + db + (tid & 15);
            s_bias[tid] = bih[row] + bhh[row];
        }
        if (tid < 80) {
            int row = (tid >> 4) * Hh + db + (tid & 15);
            s_tbias[tid] = tlb[row] + trb[row];
        }
        for (int i = tid; i < 196 * 16; i += NTHR) s_V[i] = 0.0f;
        __syncthreads();
        if (wave == 0) {              // initial x_b = read_buffer(ones)
            float sbv = (lane < Ss) ? s_sb[lane] : 0.0f;
            float P = wave_iscan(sbv, lane);
            float wbe = fminf(P, 1.0f) - fminf(P - sbv, 1.0f);
            if (lane < Ss) s_wbe[lane] = wbe;
            float axb = 0.0f;
            #pragma unroll
            for (int j = 0; j < 12; j++) {
                int s = ms * 12 + j;
                axb = fmaf(s_wbe[s], s_B[s * 16 + dl], axb);
            }
            axb = wred_ms(axb);
            if (lane < 16) {
                float* xte = XTg + (size_t)e * H3;
                st_co(xte + db + dl, axb);
                st_co(xte + 256 + db + dl, 0.0f);
                st_co(xte + 512 + db + dl, 0.0f);
            }
        }
    }
    gbar(cnt, ++barnum * 16);

    // ================= time loop =================
    for (int t = 0; t < TT; t++) {
        const int idx  = 191 - 2 * t;
        const int idx2 = idx - 1;

        // ---------- Phase L: stage full xt, LSTM matvec (wave-per-row) ----------
        {
            if (tid < 192) {
                vf4 v;
                ld_co_v4_1((const vf4*)XTg + (size_t)e * 192 + tid, v);
                ((vf4*)s_xt)[tid] = v;
            }
            __syncthreads();
            vf4 xr0 = ((const vf4*)s_xt)[lane];
            vf4 xr1 = ((const vf4*)s_xt)[64 + lane];
            vf4 xr2 = ((const vf4*)s_xt)[128 + lane];
            vf4 hr  = ((const vf4*)s_h)[lane];
            #pragma unroll 2
            for (int p = 0; p < 16; p++) {
                int r = wave * 16 + p;                    // gate = wave, dim = p
                int row = (wave << 8) + db + p;
                const vf4* w  = (const vf4*)wih + (size_t)row * 192;
                const vf4* wh = (const vf4*)whh + (size_t)row * 64;
                vf4 w0 = w[lane], w1 = w[64 + lane], w2 = w[128 + lane], w3 = wh[lane];
                vf4 acc = {0.f, 0.f, 0.f, 0.f};
                FMA4(acc, w0, xr0); FMA4(acc, w1, xr1);
                FMA4(acc, w2, xr2); FMA4(acc, w3, hr);
                float sv = wred64(acc.x + acc.y + acc.z + acc.w);
                if (lane == 0) s_g[r] = sv + s_bias[r];
            }
            __syncthreads();
            if (tid < 16) {
                float gi = s_g[tid], gf = s_g[16 + tid], gg = s_g[32 + tid], go = s_g[48 + tid];
                float cv = sigf(gf) * s_c[tid] + sigf(gi) * tanhf(gg);
                s_c[tid] = cv;
                float hv = sigf(go) * tanhf(cv);
                st_co(Hbg + (size_t)e * Hh + db + tid, hv);
            }
        }
        gbar(cnt, ++barnum * 16);

        // ---------- Phase T1: wave0 = stack path, wave1 = buffer path ----------
        if (wave < 2) {
            // both waves load full h independently (no cross-wave sync needed)
            float h0, h1, h2, h3;
            const float* hb = Hbg + (size_t)e * Hh + lane;
            ld_co_f1x4(hb, hb + 64, hb + 128, hb + 192, h0, h1, h2, h3);
            if (wave == 0) {          // stage for next L's whh matvec
                s_h[lane] = h0;       s_h[64 + lane] = h1;
                s_h[128 + lane] = h2; s_h[192 + lane] = h3;
            }
            float lg0 = h0 * aw[lane] + h1 * aw[64 + lane] + h2 * aw[128 + lane] + h3 * aw[192 + lane];
            float lg1 = h0 * aw[256 + lane] + h1 * aw[320 + lane] + h2 * aw[384 + lane] + h3 * aw[448 + lane];
            lg0 = wred64(lg0) + ab[0];
            lg1 = wred64(lg1) + ab[1];
            float a_r = 1.0f / (1.0f + expf(10.0f * (lg1 - lg0)));
            float a_s = 1.0f / (1.0f + expf(10.0f * (lg0 - lg1)));

            if (wave == 0) {
                // ----- stack pop scan -----
                int m0 = lane * 4;
                float v0 = (m0     < Mm) ? s_s[m0]     : 0.0f;
                float v1 = (m0 + 1 < Mm) ? s_s[m0 + 1] : 0.0f;
                float v2 = (m0 + 2 < Mm) ? s_s[m0 + 2] : 0.0f;
                float v3 = (m0 + 3 < Mm) ? s_s[m0 + 3] : 0.0f;
                float c1 = v0 + v1, c2 = c1 + v2, c3 = c2 + v3;
                float inc = c3;
                #pragma unroll
                for (int off = 1; off < 64; off <<= 1) {
                    float u = __shfl_up(inc, off, 64);
                    if (lane >= off) inc += u;
                }
                float ex = inc - c3;
                float Pv[4]  = {ex + v0, ex + c1, ex + c2, ex + c3};
                float Pp[4]  = {ex, ex + v0, ex + c1, ex + c2};
                float vv_[4] = {v0, v1, v2, v3};
                float sn[4];
                #pragma unroll
                for (int i = 0; i < 4; i++) {
                    int m = m0 + i;
                    float w1 = fminf(Pv[i], a_r) - fminf(Pp[i], a_r);
                    float wt = fminf(Pv[i], 1.0f + a_r) - fminf(Pp[i], 1.0f + a_r);
                    float s2 = vv_[i] - wt;
                    if (m == idx)  s2 = a_r;
                    if (m == idx2) s2 = a_s;
                    sn[i] = s2;
                    if (m < Mm) {
                        sw1[m] = w1;
                        sw2[m] = wt - w1;
                        s_s[m] = s2;
                    } else if (m < 208) {
                        sw1[m] = 0.0f; sw2[m] = 0.0f;
                    }
                }
                // ----- stack push scan (alpha=1) on updated s; FULL weights -----
                float d1 = sn[0] + sn[1], d2 = d1 + sn[2], d3 = d2 + sn[3];
                float inc2 = d3;
                #pragma unroll
                for (int off = 1; off < 64; off <<= 1) {
                    float u = __shfl_up(inc2, off, 64);
                    if (lane >= off) inc2 += u;
                }
                float ex2 = inc2 - d3;
                float Qv[4] = {ex2 + sn[0], ex2 + d1, ex2 + d2, ex2 + d3};
                float Qp[4] = {ex2, ex2 + sn[0], ex2 + d1, ex2 + d2};
                #pragma unroll
                for (int i = 0; i < 4; i++) {
                    int m = m0 + i;
                    if (m < Mm) {
                        float w1e = fminf(Qv[i], 1.0f) - fminf(Qp[i], 1.0f);
                        pw1[m] = w1e;
                        pw2[m] = (fminf(Qv[i], 2.0f) - fminf(Qp[i], 2.0f)) - w1e;
                    } else if (m < 208) {
                        pw1[m] = 0.0f; pw2[m] = 0.0f;
                    }
                }
                // ----- pop V-loop from LDS: r1/r2 (sw[idx]=sw[idx2]=0 by math) -----
                float a1 = 0.0f, a2 = 0.0f;
                #pragma unroll 7
                for (int k = 0; k < 49; k++) {
                    int m = ms * 49 + k;                  // covers 0..195; pads are 0
                    float vv = s_V[m * 16 + dl];
                    a1 = fmaf(sw1[m], vv, a1);
                    a2 = fmaf(sw2[m], vv, a2);
                }
                a1 = wred_ms(a1); a2 = wred_ms(a2);
                if (lane < 16) {
                    st_co(R1g + (size_t)e * Hh + db + dl, a1);
                    st_co(R2g + (size_t)e * Hh + db + dl, a2);
                }
            } else {
                // ----- buffer pop + push scans -----
                float sbv = (lane < Ss) ? s_sb[lane] : 0.0f;
                float Pb = wave_iscan(sbv, lane);
                float wb = fminf(Pb, a_s) - fminf(Pb - sbv, a_s);
                float sbn = sbv - wb;
                float Pb2 = wave_iscan(sbn, lane);
                float wbe = fminf(Pb2, 1.0f) - fminf(Pb2 - sbn, 1.0f);
                if (lane < Ss) { s_sb[lane] = sbn; s_wb[lane] = wb; s_wbe[lane] = wbe; }
                // ----- buffer dots: buf -> V[idx2] (LDS), axb -> XT[0:256] -----
                float abf = 0.0f, axb = 0.0f;
                #pragma unroll
                for (int j = 0; j < 12; j++) {
                    int s = ms * 12 + j;
                    float be = s_B[s * 16 + dl];
                    abf = fmaf(s_wb[s], be, abf);
                    axb = fmaf(s_wbe[s], be, axb);
                }
                abf = wred_ms(abf); axb = wred_ms(axb);
                if (lane < 16) {
                    s_V[idx2 * 16 + dl] = abf;   // racing pop-loop reads see weight 0
                    st_co(XTg + (size_t)e * H3 + db + dl, axb);
                }
            }
        }
        gbar(cnt, ++barnum * 16);

        // ---------- Phase T2: stage r1/r2, tree matvec, combine, push V-loop ----------
        {
            if (tid < 64) {
                vf4 v; ld_co_v4_1((const vf4*)R1g + (size_t)e * 64 + tid, v);
                ((vf4*)s_r1)[tid] = v;
            } else if (tid < 128) {
                vf4 v; ld_co_v4_1((const vf4*)R2g + (size_t)e * 64 + (tid - 64), v);
                ((vf4*)s_r2)[tid - 64] = v;
            }
            __syncthreads();
            vf4 r1v = ((const vf4*)s_r1)[lane];
            vf4 r2v = ((const vf4*)s_r2)[lane];
            #pragma unroll 2
            for (int p = 0; p < 20; p++) {
                int r = wave * 20 + p;
                int row = ((r >> 4) << 8) + db + (r & 15);
                const vf4* wl = (const vf4*)tlw + (size_t)row * 64;
                const vf4* wr = (const vf4*)trw + (size_t)row * 64;
                vf4 u = wl[lane], v = wr[lane];
                vf4 acc = {0.f, 0.f, 0.f, 0.f};
                FMA4(acc, u, r1v); FMA4(acc, v, r2v);
                float sv = wred64(acc.x + acc.y + acc.z + acc.w);
                if (lane == 0) s_tg[r] = sv + s_tbias[r];
            }
            __syncthreads();
            if (tid < 16) {
                float ta  = s_tg[tid];
                float ti  = s_tg[16 + tid];
                float tf1 = s_tg[32 + tid];
                float tf2 = s_tg[48 + tid];
                float to  = s_tg[64 + tid];
                float r1d = s_r1[db + tid];
                float r2d = s_r2[db + tid];
                float ct = tanhf(ta) * sigf(ti) + sigf(tf1) * r1d + sigf(tf2) * r2d;
                s_V[idx * 16 + tid] = sigf(to) * tanhf(ct);
            }
            __syncthreads();
            if (wave == 0) {   // push V-loop over fully-updated V (incl idx, idx2)
                float x1 = 0.0f, x2 = 0.0f;
                #pragma unroll 7
                for (int k = 0; k < 49; k++) {
                    int m = ms * 49 + k;
                    float vv = s_V[m * 16 + dl];
                    x1 = fmaf(pw1[m], vv, x1);
                    x2 = fmaf(pw2[m], vv, x2);
                }
                x1 = wred_ms(x1); x2 = wred_ms(x2);
                if (lane < 16) {
                    st_co(XTg + (size_t)e * H3 + 256 + db + dl, x1);
                    st_co(XTg + (size_t)e * H3 + 512 + db + dl, x2);
                }
            }
        }
        gbar(cnt, ++barnum * 16);
    }

    // ================= MLP head =================
    {   // layer 0: input = XT[:, 256:512]
        if (tid < 64) {
            vf4 v; ld_co_v4_1((const vf4*)XTg + (size_t)e * 192 + 64 + tid, v);
            ((vf4*)s_y)[tid] = v;
        }
        __syncthreads();
        vf4 xin = ((const vf4*)s_y)[lane];
        #pragma unroll 2
        for (int p = 0; p < 16; p++) {
            int row = q * 64 + wave * 16 + p;
            const vf4* w = (const vf4*)l0w + (size_t)row * 64;
            vf4 wv = w[lane];
            vf4 acc = {0.f, 0.f, 0.f, 0.f};
            FMA4(acc, wv, xin);
            float sv = wred64(acc.x + acc.y + acc.z + acc.w);
            if (lane == 0) st_co(Y0g + (size_t)e * MLPD + row, fmaxf(sv + l0b[row], 0.0f));
        }
    }
    gbar(cnt, ++barnum * 16);
    {   // layer 1: K=1024
        {
            vf4 v; ld_co_v4_1((const vf4*)Y0g + (size_t)e * 256 + tid, v);
            ((vf4*)s_y)[tid] = v;
        }
        __syncthreads();
        vf4 y0 = ((const vf4*)s_y)[lane],       y1 = ((const vf4*)s_y)[64 + lane];
        vf4 y2 = ((const vf4*)s_y)[128 + lane], y3 = ((const vf4*)s_y)[192 + lane];
        #pragma unroll 2
        for (int p = 0; p < 16; p++) {
            int row = q * 64 + wave * 16 + p;
            const vf4* w = (const vf4*)l1w + (size_t)row * 256;
            vf4 w0 = w[lane], w1 = w[64 + lane], w2 = w[128 + lane], w3 = w[192 + lane];
            vf4 acc = {0.f, 0.f, 0.f, 0.f};
            FMA4(acc, w0, y0); FMA4(acc, w1, y1); FMA4(acc, w2, y2); FMA4(acc, w3, y3);
            float sv = wred64(acc.x + acc.y + acc.z + acc.w);
            if (lane == 0) st_co(Y1g + (size_t)e * MLPD + row, fmaxf(sv + l1b[row], 0.0f));
        }
    }
    gbar(cnt, ++barnum * 16);
    if (q == 0) {  // layer 2: one block per element
        {
            vf4 v; ld_co_v4_1((const vf4*)Y1g + (size_t)e * 256 + tid, v);
            ((vf4*)s_y)[tid] = v;
        }
        __syncthreads();
        if (tid < 192) {
            int r = tid >> 6;
            const vf4* w = (const vf4*)l2w + (size_t)r * 256;
            vf4 acc = {0.f, 0.f, 0.f, 0.f};
            #pragma unroll
            for (int j = 0; j < 4; j++) {
                vf4 wv = w[lane + j * 64], yv = ((const vf4*)s_y)[lane + j * 64];
                FMA4(acc, wv, yv);
            }
            float sv = wred64(acc.x + acc.y + acc.z + acc.w);
            if (lane == 0) out[e * 3 + r] = sv + l2b[r];
        }
    }
}

extern "C" void kernel_launch(void* const* d_in, const int* in_sizes, int n_in,
                              void* d_out, int out_size, void* d_ws, size_t ws_size,
                              hipStream_t stream) {
    (void)in_sizes; (void)n_in; (void)out_size; (void)ws_size;
    (void)hipMemsetAsync(d_ws, 0, 8192, stream);  // 64 group counters x 128B

    const int*   x_   = (const int*)d_in[0];
    const float* emb  = (const float*)d_in[1];
    const float* wih  = (const float*)d_in[2];
    const float* whh  = (const float*)d_in[3];
    const float* bih  = (const float*)d_in[4];
    const float* bhh  = (const float*)d_in[5];
    const float* aw   = (const float*)d_in[6];
    const float* ab   = (const float*)d_in[7];
    const float* tlw  = (const float*)d_in[8];
    const float* tlb  = (const float*)d_in[9];
    const float* trw  = (const float*)d_in[10];
    const float* trb  = (const float*)d_in[11];
    const float* l0w  = (const float*)d_in[12];
    const float* l0b  = (const float*)d_in[13];
    const float* l1w  = (const float*)d_in[14];
    const float* l1b  = (const float*)d_in[15];
    const float* l2w  = (const float*)d_in[16];
    const float* l2b  = (const float*)d_in[17];

    float* wsf = (float*)((char*)d_ws + 8192);
    unsigned* bar = (unsigned*)d_ws;

    spinn_kernel<<<dim3(NBLK), dim3(NTHR), 0, stream>>>(
        x_, emb, wih, whh, bih, bhh, aw, ab, tlw, tlb, trw, trb,
        l0w, l0b, l1w, l1b, l2w, l2b, (float*)d_out, wsf, bar);
}